// Round 1
// baseline (8585.800 us; speedup 1.0000x reference)
//
#include <hip/hip_runtime.h>

#define HH 256
#define WW 256

// ---------------- 3x3 conv + ReLU, NCHW, 16 output channels ----------------
template<int CIN>
__global__ __launch_bounds__(256) void conv3x3_relu(
    const float* __restrict__ in, const float* __restrict__ wgt,
    const float* __restrict__ bias, float* __restrict__ out)
{
    __shared__ float w_lds[16 * CIN * 9];
    __shared__ float b_lds[16];
    for (int e = threadIdx.x; e < 16 * CIN * 9; e += 256) w_lds[e] = wgt[e];
    if (threadIdx.x < 16) b_lds[threadIdx.x] = bias[threadIdx.x];
    __syncthreads();

    int gid = blockIdx.x * 256 + threadIdx.x;   // over N*H*W = 262144
    int wx = gid & (WW - 1);
    int hy = (gid >> 8) & (HH - 1);
    int n  = gid >> 16;

    float acc[16];
#pragma unroll
    for (int o = 0; o < 16; ++o) acc[o] = b_lds[o];

#pragma unroll
    for (int ci = 0; ci < CIN; ++ci) {
        float v[9];
#pragma unroll
        for (int dy = 0; dy < 3; ++dy)
#pragma unroll
            for (int dx = 0; dx < 3; ++dx) {
                int yy = hy + dy - 1, xx = wx + dx - 1;
                bool ok = (yy >= 0) && (yy < HH) && (xx >= 0) && (xx < WW);
                v[dy*3+dx] = ok ? in[((n*CIN + ci)*HH + yy)*WW + xx] : 0.f;
            }
#pragma unroll
        for (int o = 0; o < 16; ++o) {
            const float* wp = &w_lds[(o*CIN + ci)*9];
            float a = acc[o];
#pragma unroll
            for (int k = 0; k < 9; ++k) a = fmaf(v[k], wp[k], a);
            acc[o] = a;
        }
    }
#pragma unroll
    for (int o = 0; o < 16; ++o)
        out[((n*16 + o)*HH + hy)*WW + wx] = fmaxf(acc[o], 0.f);
}

// ---- fused Pos2Weight MLP (layer1+layer2) + locally-connected contraction ----
// Block: 256 threads, 16 consecutive positions p0..p0+15.
// 16 consecutive p share (hh, s1) and span ww0..ww0+7 (s2 in {0,1}).
// Thread (r = t/16, lane = t%16): row r, lw columns lane*27 + i (i=0..26)
//   col = lane*27+i  <->  c_in = lane, (dy,dx) from i/3, rgb c = i%3.
__global__ __launch_bounds__(256) void mlp_lc_kernel(
    const float* __restrict__ pos, const float* __restrict__ w1,
    const float* __restrict__ b1,  const float* __restrict__ w2,
    const float* __restrict__ b2,  const float* __restrict__ f,
    float* __restrict__ out)
{
    __shared__ float h_lds[16][256];         // 16 KB
    __shared__ float pos_lds[16][3];
    __shared__ float f_lds[4][16][3][12];    // 9 KB: n, c_in, dy, x (10 used)

    const int t  = threadIdx.x;
    const int p0 = blockIdx.x * 16;

    if (t < 48) pos_lds[t/3][t%3] = pos[p0*3 + t];

    const int t2  = p0 >> 9;           // hh*2 + s1
    const int ww0 = (p0 >> 1) & (WW - 1);
    const int s1  = t2 & 1;
    const int hh  = t2 >> 1;

    // stage f neighborhood: rows hh-1..hh+1, cols ww0-1..ww0+8, all n, c_in
    for (int e = t; e < 4*16*3*12; e += 256) {
        int xx = e % 12; int rest = e / 12;
        int dy = rest % 3; rest /= 3;
        int ci = rest & 15; int n = rest >> 4;
        int gy = hh + dy - 1, gx = ww0 + xx - 1;
        float v = 0.f;
        if (xx < 10 && gy >= 0 && gy < HH && gx >= 0 && gx < WW)
            v = f[((n*16 + ci)*HH + gy)*WW + gx];
        f_lds[n][ci][dy][xx] = v;
    }
    __syncthreads();

    // phase A: h[r][t] = relu(pos[r] . w1[:,t] + b1[t])
#pragma unroll
    for (int i = 0; i < 16; ++i) {
        float a = fmaf(pos_lds[i][0], w1[t],
                  fmaf(pos_lds[i][1], w1[256 + t],
                  fmaf(pos_lds[i][2], w1[512 + t], b1[t])));
        h_lds[i][t] = fmaxf(a, 0.f);
    }
    __syncthreads();

    // phase B: 27 lw accumulators per thread, K = 256
    const int r    = t >> 4;
    const int lane = t & 15;
    float acc[27];
#pragma unroll
    for (int i = 0; i < 27; ++i) acc[i] = 0.f;

    const float* hrow   = &h_lds[r][0];
    const float* w2base = w2 + lane*27;
    for (int j = 0; j < 256; ++j) {
        float hv = hrow[j];
        const float* w2row = w2base + j*432;
#pragma unroll
        for (int i = 0; i < 27; ++i)
            acc[i] = fmaf(hv, w2row[i], acc[i]);
    }

    // phase C: contract with f neighborhood (cols) -> 12 partials
    const int p    = p0 + r;
    const int s2   = p & 1;
    const int xloc = r >> 1;     // ww - ww0

    float part[4][3];
#pragma unroll
    for (int n = 0; n < 4; ++n)
#pragma unroll
        for (int c = 0; c < 3; ++c) part[n][c] = 0.f;

#pragma unroll
    for (int i = 0; i < 27; ++i) {
        const int kk = i / 3;            // patch index 0..8
        const int c  = i % 3;            // rgb channel (compile-time)
        const int dy = kk / 3, dx = kk % 3;
        float lwv = acc[i] + b2[lane*27 + i];
#pragma unroll
        for (int n = 0; n < 4; ++n)
            part[n][c] += f_lds[n][lane][dy][xloc + dx] * lwv;
    }

    // phase D: reduce across the 16 lanes of this row group
#pragma unroll
    for (int n = 0; n < 4; ++n)
#pragma unroll
        for (int c = 0; c < 3; ++c) {
            float v = part[n][c];
            v += __shfl_down(v, 8, 16);
            v += __shfl_down(v, 4, 16);
            v += __shfl_down(v, 2, 16);
            v += __shfl_down(v, 1, 16);
            part[n][c] = v;
        }

    if (lane == 0) {
        const int oy = hh*2 + s1;
        const int ox = (ww0 + xloc)*2 + s2;
#pragma unroll
        for (int n = 0; n < 4; ++n) {
            out[((n*3 + 0)*512 + oy)*512 + ox] = part[n][0] + 114.4440f;
            out[((n*3 + 1)*512 + oy)*512 + ox] = part[n][1] + 111.4605f;
            out[((n*3 + 2)*512 + oy)*512 + ox] = part[n][2] + 103.0200f;
        }
    }
}

extern "C" void kernel_launch(void* const* d_in, const int* in_sizes, int n_in,
                              void* d_out, int out_size, void* d_ws, size_t ws_size,
                              hipStream_t stream) {
    const float* x    = (const float*)d_in[0];
    const float* pos  = (const float*)d_in[1];
    const float* c0w  = (const float*)d_in[2];
    const float* c0b  = (const float*)d_in[3];
    const float* c1w  = (const float*)d_in[4];
    const float* c1b  = (const float*)d_in[5];
    const float* c2w  = (const float*)d_in[6];
    const float* c2b  = (const float*)d_in[7];
    const float* c3w  = (const float*)d_in[8];
    const float* c3b  = (const float*)d_in[9];
    const float* w1   = (const float*)d_in[10];
    const float* b1   = (const float*)d_in[11];
    const float* w2   = (const float*)d_in[12];
    const float* b2   = (const float*)d_in[13];
    float* out = (float*)d_out;

    float* f0 = (float*)d_ws;                 // 4*16*256*256 floats = 16 MB
    float* f1 = f0 + 4u*16u*256u*256u;        // second ping-pong buffer

    conv3x3_relu<3> <<<1024, 256, 0, stream>>>(x,  c0w, c0b, f0);
    conv3x3_relu<16><<<1024, 256, 0, stream>>>(f0, c1w, c1b, f1);
    conv3x3_relu<16><<<1024, 256, 0, stream>>>(f1, c2w, c2b, f0);
    conv3x3_relu<16><<<1024, 256, 0, stream>>>(f0, c3w, c3b, f1);

    mlp_lc_kernel<<<262144/16, 256, 0, stream>>>(pos, w1, b1, w2, b2, f1, out);
}

// Round 2
// 587.665 us; speedup vs baseline: 14.6100x; 14.6100x over previous
//
#include <hip/hip_runtime.h>

typedef _Float16 half8 __attribute__((ext_vector_type(8)));
typedef float float4v __attribute__((ext_vector_type(4)));

#define HH 256
#define WW 256

// ---------------- 3x3 conv + ReLU, NCHW, 16 output channels ----------------
// Tile 64x4 pixels/block. Input tile staged in LDS; weights read via
// wave-uniform global addresses -> s_load (SGPR operands, no LDS broadcast).
template<int CIN>
__global__ __launch_bounds__(256) void conv3x3_relu(
    const float* __restrict__ in, const float* __restrict__ wgt,
    const float* __restrict__ bias, float* __restrict__ out)
{
    __shared__ float tile[CIN][6][66];

    const int t = threadIdx.x;
    const int bid = blockIdx.x;
    const int xt = bid & 3, yt = (bid >> 2) & 63, n = bid >> 8;
    const int x0 = xt * 64, y0 = yt * 4;

    for (int e = t; e < CIN * 6 * 66; e += 256) {
        int ci = e / 396;
        int rem = e - ci * 396;
        int ry = rem / 66;
        int rx = rem - ry * 66;
        int gy = y0 + ry - 1, gx = x0 + rx - 1;
        float v = 0.f;
        if (gy >= 0 && gy < HH && gx >= 0 && gx < WW)
            v = in[((n * CIN + ci) * HH + gy) * WW + gx];
        tile[ci][ry][rx] = v;
    }
    __syncthreads();

    const int x = t & 63, y = t >> 6;
    float acc[16];
#pragma unroll
    for (int o = 0; o < 16; ++o) acc[o] = bias[o];

    for (int ci = 0; ci < CIN; ++ci) {
        float v[9];
#pragma unroll
        for (int dy = 0; dy < 3; ++dy)
#pragma unroll
            for (int dx = 0; dx < 3; ++dx)
                v[dy * 3 + dx] = tile[ci][y + dy][x + dx];
#pragma unroll
        for (int o = 0; o < 16; ++o) {
#pragma unroll
            for (int k = 0; k < 9; ++k)
                acc[o] = fmaf(v[k], wgt[(o * CIN + ci) * 9 + k], acc[o]);
        }
    }
    const int gy = y0 + y, gx = x0 + x;
#pragma unroll
    for (int o = 0; o < 16; ++o)
        out[((n * 16 + o) * HH + gy) * WW + gx] = fmaxf(acc[o], 0.f);
}

// ---------------- pack w2 (256x432 f32) into A-fragment order, f16 ----------
// A-tile t (16 cols), k-step s (32 k): lane l, elem j holds
//   w2[k = 32s + (l>>4)*8 + j][col = 16t + (l&15)]
__global__ __launch_bounds__(256) void pack_w2(
    const float* __restrict__ w2, half8* __restrict__ w2p)
{
    int tid = blockIdx.x * 256 + threadIdx.x;    // < 27*8*64 = 13824
    int l  = tid & 63;
    int s  = (tid >> 6) & 7;
    int tt = tid >> 9;
    int kbase = s * 32 + (l >> 4) * 8;
    int col   = tt * 16 + (l & 15);
    half8 h;
#pragma unroll
    for (int j = 0; j < 8; ++j)
        h[j] = (_Float16)w2[(kbase + j) * 432 + col];
    w2p[tid] = h;
}

// ---- fused Pos2Weight MLP (MFMA) + locally-connected contraction ----------
// Block: 256 thr = 4 waves, 64 positions. GEMM C[col][pos] = w2^T . h^T:
// each wave owns a 7-tile (6 for wave 3) slice of the 27 N=16 col-tiles,
// all 64 positions. Swapped operands put one position per lane -> epilogue
// reduce is 2 shfl_xor; rgb index rotation kept compile-time via (ti+reg)%3.
__global__ __launch_bounds__(256) void mlp_lc_mfma(
    const float* __restrict__ pos, const float* __restrict__ w1,
    const float* __restrict__ b1,  const half8* __restrict__ w2p,
    const float* __restrict__ b2,  const float* __restrict__ f,
    float* __restrict__ out)
{
    __shared__ __attribute__((aligned(16))) _Float16 h_lds[64][264]; // 33792 B (aliased as part_lds)
    __shared__ float f_lds[16][3][34][4];                            // 26112 B [ci][dy][x][n]
    __shared__ float pos_lds[64][4];

    const int t   = threadIdx.x;
    const int p0  = blockIdx.x * 64;
    const int t2  = p0 >> 9;                  // oy = hh*2 + s1
    const int hh  = t2 >> 1;
    const int ww0 = (p0 >> 1) & (WW - 1);

    if (t < 192) pos_lds[t / 3][t % 3] = pos[p0 * 3 + t];

    for (int e = t; e < 16 * 3 * 34 * 4; e += 256) {   // ordered (n,ci,dy,x)
        int x  = e % 34;
        int r1 = e / 34;
        int dy = r1 % 3;
        int r2 = r1 / 3;
        int ci = r2 & 15;
        int n  = r2 >> 4;
        int gy = hh + dy - 1, gx = ww0 + x - 1;
        float v = 0.f;
        if (gy >= 0 && gy < HH && gx >= 0 && gx < WW)
            v = f[((n * 16 + ci) * HH + gy) * WW + gx];
        f_lds[ci][dy][x][n] = v;
    }
    __syncthreads();

    // ---- h = relu(pos @ w1 + b1), f16, padded stride 264 ----
    {
        const int k = t;
        float wa = w1[k], wb = w1[256 + k], wc = w1[512 + k], bb = b1[k];
#pragma unroll 8
        for (int i = 0; i < 64; ++i) {
            float4v pv = *(const float4v*)&pos_lds[i][0];
            float a = fmaf(pv[0], wa, fmaf(pv[1], wb, fmaf(pv[2], wc, bb)));
            h_lds[i][k] = (_Float16)fmaxf(a, 0.f);
        }
    }
    __syncthreads();

    // ---- GEMM ----
    const int wid  = t >> 6;
    const int lane = t & 63;
    const int l15  = lane & 15, hi = lane >> 4;
    const int tb   = wid * 7;                 // 0,7,14,21 (wave 3 has 6 tiles)

    float4v acc[7][4];
#pragma unroll
    for (int ti = 0; ti < 7; ++ti)
        if (tb + ti < 27) {
            float4v binit = *(const float4v*)&b2[(tb + ti) * 16 + hi * 4];
#pragma unroll
            for (int pg = 0; pg < 4; ++pg) acc[ti][pg] = binit;
        }

    for (int ks = 0; ks < 8; ++ks) {
        half8 bfrag[4];
#pragma unroll
        for (int pg = 0; pg < 4; ++pg)
            bfrag[pg] = *(const half8*)&h_lds[pg * 16 + l15][ks * 32 + hi * 8];
#pragma unroll
        for (int ti = 0; ti < 7; ++ti)
            if (tb + ti < 27) {
                half8 afrag = w2p[((tb + ti) * 8 + ks) * 64 + lane];
#pragma unroll
                for (int pg = 0; pg < 4; ++pg)
                    acc[ti][pg] = __builtin_amdgcn_mfma_f32_16x16x32_f16(
                        afrag, bfrag[pg], acc[ti][pg], 0, 0, 0);
            }
    }
    __syncthreads();   // h_lds dead; part_lds aliases it below

    // ---- epilogue: per (ti,reg) col -> (rgb c, ci, dy, dx) ----
    const float* fbase = &f_lds[0][0][0][0];
    int abase[7][4];
#pragma unroll
    for (int ti = 0; ti < 7; ++ti)
#pragma unroll
        for (int reg = 0; reg < 4; ++reg) {
            int col = (tb + ti) * 16 + hi * 4 + reg;
            unsigned s  = (unsigned)col / 3u;
            unsigned ci = s / 9u;
            unsigned kk = s - 9u * ci;
            unsigned dy = kk / 3u;
            unsigned dx = kk - 3u * dy;
            abase[ti][reg] = (int)(((ci * 3 + dy) * 34 + dx) * 4);
        }

    float* part_lds = (float*)&h_lds[0][0];   // [4][64][13]
    const int r3 = (tb + hi) % 3;

#pragma unroll
    for (int pg = 0; pg < 4; ++pg) {
        float part[4][3];
#pragma unroll
        for (int n = 0; n < 4; ++n)
#pragma unroll
            for (int c = 0; c < 3; ++c) part[n][c] = 0.f;

        const int posl = pg * 16 + l15;
        const int xloc = posl >> 1;
#pragma unroll
        for (int ti = 0; ti < 7; ++ti)
            if (tb + ti < 27) {
#pragma unroll
                for (int reg = 0; reg < 4; ++reg) {
                    float4v fv = *(const float4v*)&fbase[abase[ti][reg] + xloc * 4];
                    float av = acc[ti][pg][reg];
                    const int u = (ti + reg) % 3;
#pragma unroll
                    for (int n = 0; n < 4; ++n)
                        part[n][u] = fmaf(av, fv[n], part[n][u]);
                }
            }

        float real[4][3];
#pragma unroll
        for (int n = 0; n < 4; ++n)
#pragma unroll
            for (int c = 0; c < 3; ++c)
                real[n][c] = (r3 == 0) ? part[n][c]
                           : (r3 == 1) ? part[n][(c + 2) % 3]
                                       : part[n][(c + 1) % 3];
#pragma unroll
        for (int n = 0; n < 4; ++n)
#pragma unroll
            for (int c = 0; c < 3; ++c) {
                float v = real[n][c];
                v += __shfl_xor(v, 16);
                v += __shfl_xor(v, 32);
                if (hi == 0)
                    part_lds[(wid * 64 + posl) * 13 + n * 3 + c] = v;
            }
    }
    __syncthreads();

    // ---- combine 4 waves' partials, add mean, store ----
#pragma unroll
    for (int e = t; e < 768; e += 256) {
        int posl = e & 63;
        int j = e >> 6;                       // n*3+c
        float v = part_lds[(0 * 64 + posl) * 13 + j]
                + part_lds[(1 * 64 + posl) * 13 + j]
                + part_lds[(2 * 64 + posl) * 13 + j]
                + part_lds[(3 * 64 + posl) * 13 + j];
        int n = j / 3, c = j - 3 * n;
        float mean = (c == 0) ? 114.4440f : (c == 1) ? 111.4605f : 103.0200f;
        out[((n * 3 + c) * 512 + t2) * 512 + (ww0 * 2 + posl)] = v + mean;
    }
}

extern "C" void kernel_launch(void* const* d_in, const int* in_sizes, int n_in,
                              void* d_out, int out_size, void* d_ws, size_t ws_size,
                              hipStream_t stream) {
    const float* x    = (const float*)d_in[0];
    const float* pos  = (const float*)d_in[1];
    const float* c0w  = (const float*)d_in[2];
    const float* c0b  = (const float*)d_in[3];
    const float* c1w  = (const float*)d_in[4];
    const float* c1b  = (const float*)d_in[5];
    const float* c2w  = (const float*)d_in[6];
    const float* c2b  = (const float*)d_in[7];
    const float* c3w  = (const float*)d_in[8];
    const float* c3b  = (const float*)d_in[9];
    const float* w1   = (const float*)d_in[10];
    const float* b1   = (const float*)d_in[11];
    const float* w2   = (const float*)d_in[12];
    const float* b2   = (const float*)d_in[13];
    float* out = (float*)d_out;

    float* f0 = (float*)d_ws;                 // 16 MB
    float* f1 = f0 + 4u * 16u * 256u * 256u;  // 16 MB

    conv3x3_relu<3> <<<1024, 256, 0, stream>>>(x,  c0w, c0b, f0);
    conv3x3_relu<16><<<1024, 256, 0, stream>>>(f0, c1w, c1b, f1);
    conv3x3_relu<16><<<1024, 256, 0, stream>>>(f1, c2w, c2b, f0);
    conv3x3_relu<16><<<1024, 256, 0, stream>>>(f0, c3w, c3b, f1);

    // f0 is dead after conv3; reuse its space for packed w2 (221 KB)
    pack_w2<<<54, 256, 0, stream>>>(w2, (half8*)d_ws);

    mlp_lc_mfma<<<4096, 256, 0, stream>>>(pos, w1, b1, (const half8*)d_ws,
                                          b2, f1, out);
}

// Round 3
// 302.966 us; speedup vs baseline: 28.3391x; 1.9397x over previous
//
#include <hip/hip_runtime.h>

typedef _Float16 half8 __attribute__((ext_vector_type(8)));
typedef float float4v __attribute__((ext_vector_type(4)));

#define HH 256
#define WW 256

// ---------------- 3x3 conv + ReLU, NCHW, 16 output channels ----------------
template<int CIN>
__global__ __launch_bounds__(256) void conv3x3_relu(
    const float* __restrict__ in, const float* __restrict__ wgt,
    const float* __restrict__ bias, float* __restrict__ out)
{
    __shared__ float tile[CIN][6][66];

    const int t = threadIdx.x;
    const int bid = blockIdx.x;
    const int xt = bid & 3, yt = (bid >> 2) & 63, n = bid >> 8;
    const int x0 = xt * 64, y0 = yt * 4;

    for (int e = t; e < CIN * 6 * 66; e += 256) {
        int ci = e / 396;
        int rem = e - ci * 396;
        int ry = rem / 66;
        int rx = rem - ry * 66;
        int gy = y0 + ry - 1, gx = x0 + rx - 1;
        float v = 0.f;
        if (gy >= 0 && gy < HH && gx >= 0 && gx < WW)
            v = in[((n * CIN + ci) * HH + gy) * WW + gx];
        tile[ci][ry][rx] = v;
    }
    __syncthreads();

    const int x = t & 63, y = t >> 6;
    float acc[16];
#pragma unroll
    for (int o = 0; o < 16; ++o) acc[o] = bias[o];

    for (int ci = 0; ci < CIN; ++ci) {
        float v[9];
#pragma unroll
        for (int dy = 0; dy < 3; ++dy)
#pragma unroll
            for (int dx = 0; dx < 3; ++dx)
                v[dy * 3 + dx] = tile[ci][y + dy][x + dx];
#pragma unroll
        for (int o = 0; o < 16; ++o) {
#pragma unroll
            for (int k = 0; k < 9; ++k)
                acc[o] = fmaf(v[k], wgt[(o * CIN + ci) * 9 + k], acc[o]);
        }
    }
    const int gy = y0 + y, gx = x0 + x;
#pragma unroll
    for (int o = 0; o < 16; ++o)
        out[((n * 16 + o) * HH + gy) * WW + gx] = fmaxf(acc[o], 0.f);
}

// ---------------- pack w2/b2 with the (kk,c)-tile, ci-slot permutation ------
// tile ti in 0..26 <-> (kk = ti/3, c = ti%3); within-tile slot = ci (0..15).
// original column = (ci*9 + kk)*3 + c.
// A-frag: lane l, k-step s, elem j holds w2[k = 32s+(l>>4)*8+j][origcol(ti, l&15)]
__global__ __launch_bounds__(256) void pack_w2(
    const float* __restrict__ w2, const float* __restrict__ b2,
    half8* __restrict__ w2p, float* __restrict__ b2p)
{
    int tid = blockIdx.x * 256 + threadIdx.x;    // < 27*8*64 = 13824
    int l  = tid & 63;
    int s  = (tid >> 6) & 7;
    int tt = tid >> 9;                           // tile 0..26
    int kk = tt / 3, c = tt % 3;
    int ci = l & 15;
    int col = (ci * 9 + kk) * 3 + c;
    int kbase = s * 32 + (l >> 4) * 8;
    half8 h;
#pragma unroll
    for (int j = 0; j < 8; ++j)
        h[j] = (_Float16)w2[(kbase + j) * 432 + col];
    w2p[tid] = h;

    if (tid < 432) {
        int tt2 = tid >> 4, ci2 = tid & 15;
        int kk2 = tt2 / 3, c2 = tt2 % 3;
        b2p[tid] = b2[(ci2 * 9 + kk2) * 3 + c2];
    }
}

// ---- fused Pos2Weight MLP (MFMA) + locally-connected contraction ----------
// 512 thr = 8 waves per block, 64 positions. 27 col-tiles split 4/4/4/3*5
// over waves. Swapped operands: C[ci-slot][pos]; lane = (hi,l15) holds
// ci = hi*4+reg for position pg*16+l15. f staged f16 [dy][x][ci][n] with
// XOR-swizzle ((x&7)<<3 on half index) -> conflict-free b128 epilogue reads.
__global__ __launch_bounds__(512, 4) void mlp_lc_mfma(
    const float* __restrict__ pos, const float* __restrict__ w1,
    const float* __restrict__ b1,  const half8* __restrict__ w2p,
    const float* __restrict__ b2p, const float* __restrict__ f,
    float* __restrict__ out)
{
    __shared__ __attribute__((aligned(16))) char smem[47872];
    _Float16* h_lds    = (_Float16*)smem;                  // [64][264] 33792 B
    _Float16* f_lds    = (_Float16*)(smem + 33792);        // 6528 halfs, 13056 B
    float*    pos_lds  = (float*)(smem + 33792 + 13056);   // [64][4] 1024 B
    float*    part_lds = (float*)smem;                     // [64][106] alias (27136 B)

    const int t   = threadIdx.x;
    const int p0  = blockIdx.x * 64;
    const int t2  = p0 >> 9;                  // output row oy
    const int hh  = t2 >> 1;
    const int ww0 = (p0 >> 1) & (WW - 1);

    if (t < 192) pos_lds[(t / 3) * 4 + (t % 3)] = pos[p0 * 3 + t];

    // stage f -> f16, logical half-index L = (dy*34+x)*64 + ci*4 + n, swizzled
    for (int e = t; e < 6528; e += 512) {
        int x  = e % 34;
        int r  = e / 34;
        int dy = r % 3;
        int r2 = r / 3;
        int ci = r2 & 15;
        int n  = r2 >> 4;
        int gy = hh + dy - 1, gx = ww0 + x - 1;
        float v = 0.f;
        if (gy >= 0 && gy < HH && gx >= 0 && gx < WW)
            v = f[((n * 16 + ci) * HH + gy) * WW + gx];
        int hidx = (((dy * 34 + x) * 64) + ci * 4 + n) ^ ((x & 7) << 3);
        f_lds[hidx] = (_Float16)v;
    }
    __syncthreads();

    // ---- h = relu(pos @ w1 + b1), f16, padded row stride 264 ----
    {
        const int k  = t & 255;
        const int i0 = (t >> 8) * 32;
        float wa = w1[k], wb = w1[256 + k], wc = w1[512 + k], bb = b1[k];
#pragma unroll 8
        for (int i = i0; i < i0 + 32; ++i) {
            float4v pv = *(const float4v*)&pos_lds[i * 4];
            float a = fmaf(pv[0], wa, fmaf(pv[1], wb, fmaf(pv[2], wc, bb)));
            h_lds[i * 264 + k] = (_Float16)fmaxf(a, 0.f);
        }
    }
    __syncthreads();

    // ---- GEMM: acc[tt][pg] = w2tile(tb+tt)^T @ h(pg) ----
    const int wid  = t >> 6;
    const int lane = t & 63;
    const int l15  = lane & 15, hi = lane >> 4;
    const int tb   = (wid <= 3) ? wid * 4 : 12 + (wid - 3) * 3;
    const int cnt  = (wid < 3) ? 4 : 3;

    float4v acc[4][4];
#pragma unroll
    for (int tt = 0; tt < 4; ++tt)
        if (tt < cnt) {
            float4v binit = *(const float4v*)&b2p[(tb + tt) * 16 + hi * 4];
#pragma unroll
            for (int pg = 0; pg < 4; ++pg) acc[tt][pg] = binit;
        }

    for (int ks = 0; ks < 8; ++ks) {
        half8 bfrag[4];
#pragma unroll
        for (int pg = 0; pg < 4; ++pg)
            bfrag[pg] = *(const half8*)&h_lds[(pg * 16 + l15) * 264 + ks * 32 + hi * 8];
#pragma unroll
        for (int tt = 0; tt < 4; ++tt)
            if (tt < cnt) {
                half8 afrag = w2p[((tb + tt) * 8 + ks) * 64 + lane];
#pragma unroll
                for (int pg = 0; pg < 4; ++pg)
                    acc[tt][pg] = __builtin_amdgcn_mfma_f32_16x16x32_f16(
                        afrag, bfrag[pg], acc[tt][pg], 0, 0, 0);
            }
    }
    __syncthreads();   // all h reads done; part_lds (alias) may be written

    // ---- epilogue: contract with f, reduce over hi (shfl) and waves (LDS) --
    const int r3 = tb % 3;            // wave-uniform rgb rotation

#pragma unroll
    for (int pg = 0; pg < 4; ++pg) {
        const int posl = pg * 16 + l15;
        const int xloc = posl >> 1;

        float part[4][3];
#pragma unroll
        for (int n = 0; n < 4; ++n)
#pragma unroll
            for (int c = 0; c < 3; ++c) part[n][c] = 0.f;

#pragma unroll
        for (int tt = 0; tt < 4; ++tt)
            if (tt < cnt) {
                int ti = tb + tt;
                int kk = ti / 3;
                int dy = kk / 3, dx = kk % 3;
                int x  = xloc + dx;
                int b0 = (((dy * 34 + x) * 64) + hi * 16) ^ ((x & 7) << 3);
                half8 fv0 = *(const half8*)&f_lds[b0];       // ci hi*4+0,1 (n 0..3)
                half8 fv1 = *(const half8*)&f_lds[b0 ^ 8];   // ci hi*4+2,3
                const int u = tt % 3;                        // compile-time slot
                float a0 = acc[tt][pg][0], a1 = acc[tt][pg][1];
                float a2 = acc[tt][pg][2], a3 = acc[tt][pg][3];
#pragma unroll
                for (int n = 0; n < 4; ++n) {
                    float s = fmaf((float)fv0[n], a0,
                              fmaf((float)fv0[4 + n], a1,
                              fmaf((float)fv1[n], a2,
                                   (float)fv1[4 + n] * a3)));
                    part[n][u] += s;
                }
            }

        // undo rgb rotation: true c = (r3 + slot) % 3 (r3 wave-uniform)
        float real[4][3];
        if (r3 == 0) {
#pragma unroll
            for (int n = 0; n < 4; ++n) {
                real[n][0] = part[n][0]; real[n][1] = part[n][1]; real[n][2] = part[n][2];
            }
        } else if (r3 == 1) {
#pragma unroll
            for (int n = 0; n < 4; ++n) {
                real[n][1] = part[n][0]; real[n][2] = part[n][1]; real[n][0] = part[n][2];
            }
        } else {
#pragma unroll
            for (int n = 0; n < 4; ++n) {
                real[n][2] = part[n][0]; real[n][0] = part[n][1]; real[n][1] = part[n][2];
            }
        }

#pragma unroll
        for (int n = 0; n < 4; ++n)
#pragma unroll
            for (int c = 0; c < 3; ++c) {
                float v = real[n][c];
                v += __shfl_xor(v, 16);
                v += __shfl_xor(v, 32);
                if (hi == 0)
                    part_lds[posl * 106 + (n * 3 + c) * 8 + wid] = v;
            }
    }
    __syncthreads();

    // ---- combine 8 waves' partials, add mean, store ----
    for (int e = t; e < 768; e += 512) {
        int posl = e & 63;
        int j = e >> 6;                       // n*3+c
        const float* pr = &part_lds[posl * 106 + j * 8];
        float4v v0 = *(const float4v*)pr;
        float4v v1 = *(const float4v*)(pr + 4);
        float v = v0[0] + v0[1] + v0[2] + v0[3] + v1[0] + v1[1] + v1[2] + v1[3];
        int n = j / 3, c = j - 3 * n;
        float mean = (c == 0) ? 114.4440f : (c == 1) ? 111.4605f : 103.0200f;
        out[((n * 3 + c) * 512 + t2) * 512 + (ww0 * 2 + posl)] = v + mean;
    }
}

extern "C" void kernel_launch(void* const* d_in, const int* in_sizes, int n_in,
                              void* d_out, int out_size, void* d_ws, size_t ws_size,
                              hipStream_t stream) {
    const float* x    = (const float*)d_in[0];
    const float* pos  = (const float*)d_in[1];
    const float* c0w  = (const float*)d_in[2];
    const float* c0b  = (const float*)d_in[3];
    const float* c1w  = (const float*)d_in[4];
    const float* c1b  = (const float*)d_in[5];
    const float* c2w  = (const float*)d_in[6];
    const float* c2b  = (const float*)d_in[7];
    const float* c3w  = (const float*)d_in[8];
    const float* c3b  = (const float*)d_in[9];
    const float* w1   = (const float*)d_in[10];
    const float* b1   = (const float*)d_in[11];
    const float* w2   = (const float*)d_in[12];
    const float* b2   = (const float*)d_in[13];
    float* out = (float*)d_out;

    float* f0 = (float*)d_ws;                 // 16 MB
    float* f1 = f0 + 4u * 16u * 256u * 256u;  // 16 MB

    conv3x3_relu<3> <<<1024, 256, 0, stream>>>(x,  c0w, c0b, f0);
    conv3x3_relu<16><<<1024, 256, 0, stream>>>(f0, c1w, c1b, f1);
    conv3x3_relu<16><<<1024, 256, 0, stream>>>(f1, c2w, c2b, f0);
    conv3x3_relu<16><<<1024, 256, 0, stream>>>(f0, c3w, c3b, f1);

    // f0 dead after conv3; reuse its space for packed w2 (221 KB) + b2 (1.7 KB)
    half8* w2p = (half8*)d_ws;
    float* b2p = (float*)((char*)d_ws + 27 * 8 * 64 * sizeof(half8));
    pack_w2<<<54, 256, 0, stream>>>(w2, b2, w2p, b2p);

    mlp_lc_mfma<<<4096, 512, 0, stream>>>(pos, w1, b1, w2p, b2p, f1, out);
}

// Round 5
// 170.926 us; speedup vs baseline: 50.2312x; 1.7725x over previous
//
#include <hip/hip_runtime.h>
#include <string.h>

typedef _Float16 half2v __attribute__((ext_vector_type(2)));
typedef _Float16 half4  __attribute__((ext_vector_type(4)));
typedef _Float16 half8  __attribute__((ext_vector_type(8)));
typedef float    float4v __attribute__((ext_vector_type(4)));
typedef unsigned int uint4v __attribute__((ext_vector_type(4)));

#define HH 256
#define WW 256

static __device__ inline half2v pkrtz(float a, float b) {
    return __builtin_bit_cast(half2v, __builtin_amdgcn_cvt_pkrtz(a, b));
}

static __device__ inline float fdot2f(half2v a, half2v b, float c) {
#if __has_builtin(__builtin_amdgcn_fdot2)
    return __builtin_amdgcn_fdot2(__builtin_bit_cast(__fp16 __attribute__((ext_vector_type(2))), a),
                                  __builtin_bit_cast(__fp16 __attribute__((ext_vector_type(2))), b),
                                  c, false);
#else
    return c + (float)a[0] * (float)b[0] + (float)a[1] * (float)b[1];
#endif
}

// ---------------- x (NCHW f32, 3ch) -> xh (NHWC f16, 16ch zero-padded) -----
__global__ __launch_bounds__(256) void xcvt(
    const float* __restrict__ x, _Float16* __restrict__ xh)
{
    int gid = blockIdx.x * 256 + threadIdx.x;      // n*65536 + y*256 + x
    int px = gid & 65535, n = gid >> 16;
    float r = x[n * 196608 + px];
    float g = x[n * 196608 + 65536 + px];
    float b = x[n * 196608 + 131072 + px];
    half2v p0 = pkrtz(r, g);
    half2v p1 = pkrtz(b, 0.f);
    unsigned u0, u1;
    memcpy(&u0, &p0, 4); memcpy(&u1, &p1, 4);
    uint4v v0 = {u0, u1, 0u, 0u};
    uint4v v1 = {0u, 0u, 0u, 0u};
    uint4v* dst = (uint4v*)&xh[(long)gid * 16];
    dst[0] = v0; dst[1] = v1;
}

// ---------------- pack conv weights into A-frag order, K=160 (tap*16+ci) ---
// wpk[conv][s][lane] half8: lane l: o=l&15, k=32s+(l>>4)*8+j -> tap=k>>4, ci=k&15
__global__ __launch_bounds__(256) void pack_wc(
    const float* __restrict__ w0, const float* __restrict__ w1c,
    const float* __restrict__ w2c, const float* __restrict__ w3c,
    half8* __restrict__ wpk)
{
    int tid = blockIdx.x * 256 + threadIdx.x;      // < 1280
    if (tid >= 1280) return;
    int l = tid & 63, s = (tid >> 6) % 5, cv = tid / 320;
    const float* w = (cv == 0) ? w0 : (cv == 1) ? w1c : (cv == 2) ? w2c : w3c;
    int CIN = (cv == 0) ? 3 : 16;
    int o = l & 15, hi = l >> 4;
    half8 h;
#pragma unroll
    for (int j = 0; j < 8; ++j) {
        int k = 32 * s + hi * 8 + j;
        int tap = k >> 4, ci = k & 15;
        float v = 0.f;
        if (tap < 9 && ci < CIN)
            v = w[((o * CIN + ci) * 3 + tap / 3) * 3 + tap % 3];
        h[j] = (_Float16)v;
    }
    wpk[tid] = h;
}

// ---------------- conv 3x3 + ReLU via implicit-GEMM MFMA, NHWC f16 ---------
// Block 256 thr / 4 waves, tile 64x x 4y. LDS tile [7][66][16] f16.
// Wave w: row ty=w, 4 px-tiles of 16. B-frag = 1 ds_read_b128 per lane.
__global__ __launch_bounds__(256) void conv_mfma(
    const _Float16* __restrict__ in, const half8* __restrict__ wpk,
    const float* __restrict__ bias, _Float16* __restrict__ outp)
{
    __shared__ _Float16 tile[7][66][16];           // 14784 B

    const int t = threadIdx.x;
    const int bid = blockIdx.x;
    const int xt = bid & 3, yt = (bid >> 2) & 63, n = bid >> 8;
    const int x0 = xt * 64, y0 = yt * 4;

    for (int e = t; e < 462; e += 256) {           // 7 rows x 66 x, 32B chunks
        int xx = e % 66, row = e / 66;
        int gy = y0 + row - 1, gx = x0 + xx - 1;
        uint4v v0 = {0u,0u,0u,0u}, v1 = {0u,0u,0u,0u};
        if (gy >= 0 && gy < HH && gx >= 0 && gx < WW) {
            const uint4v* src = (const uint4v*)&in[(((long)(n*HH+gy))*WW + gx) * 16];
            v0 = src[0]; v1 = src[1];
        }
        uint4v* dst = (uint4v*)&tile[row][xx][0];
        dst[0] = v0; dst[1] = v1;
    }
    __syncthreads();

    const int wid = t >> 6, lane = t & 63;
    const int l15 = lane & 15, hi = lane >> 4;

    half8 af[5];
#pragma unroll
    for (int s = 0; s < 5; ++s) af[s] = wpk[s * 64 + lane];
    const float4v bini = *(const float4v*)&bias[hi * 4];

    const int ty = wid;
    const half8* bp = (const half8*)&tile[0][0][0];
#pragma unroll
    for (int tx = 0; tx < 4; ++tx) {
        float4v acc = bini;
#pragma unroll
        for (int s = 0; s < 5; ++s) {
            int tap = 2 * s + (hi >> 1);
            int dyq = (tap * 11) >> 5;             // tap / 3
            int dxr = tap - dyq * 3;
            int cell = (ty + dyq) * 66 + (tx * 16 + l15 + dxr);
            half8 bf = bp[cell * 2 + (hi & 1)];
            acc = __builtin_amdgcn_mfma_f32_16x16x32_f16(af[s], bf, acc, 0, 0, 0);
        }
        int gx = x0 + tx * 16 + l15, gy = y0 + ty;
        half2v p0 = pkrtz(fmaxf(acc[0], 0.f), fmaxf(acc[1], 0.f));
        half2v p1 = pkrtz(fmaxf(acc[2], 0.f), fmaxf(acc[3], 0.f));
        half4 ov = __builtin_shufflevector(p0, p1, 0, 1, 2, 3);
        *(half4*)&outp[(((long)(n*HH+gy))*WW + gx) * 16 + hi * 4] = ov;
    }
}

// ---------------- pack w2/b2 with the (kk,c)-tile, ci-slot permutation ------
__global__ __launch_bounds__(256) void pack_w2(
    const float* __restrict__ w2, const float* __restrict__ b2,
    half8* __restrict__ w2p, float* __restrict__ b2p)
{
    int tid = blockIdx.x * 256 + threadIdx.x;    // < 27*8*64 = 13824
    int l  = tid & 63;
    int s  = (tid >> 6) & 7;
    int tt = tid >> 9;                           // tile 0..26
    int kk = tt / 3, c = tt % 3;
    int ci = l & 15;
    int col = (ci * 9 + kk) * 3 + c;
    int kbase = s * 32 + (l >> 4) * 8;
    half8 h;
#pragma unroll
    for (int j = 0; j < 8; ++j)
        h[j] = (_Float16)w2[(kbase + j) * 432 + col];
    w2p[tid] = h;

    if (tid < 432) {
        int tt2 = tid >> 4, ci2 = tid & 15;
        int kk2 = tt2 / 3, c2 = tt2 % 3;
        b2p[tid] = b2[(ci2 * 9 + kk2) * 3 + c2];
    }
}

// ---- fused Pos2Weight MLP (MFMA) + locally-connected contraction ----------
// 512 thr / 8 waves, 64 positions. f staged as 16-half cells [dy][x][n][ci]
// with cell-XOR swizzle (cell ^ (x&7)); epilogue uses v_dot2_f32_f16.
__global__ __launch_bounds__(512, 4) void mlp_lc_mfma(
    const float* __restrict__ pos, const float* __restrict__ w1,
    const float* __restrict__ b1,  const half8* __restrict__ w2p,
    const float* __restrict__ b2p, const _Float16* __restrict__ f,
    float* __restrict__ out)
{
    __shared__ __attribute__((aligned(16))) char smem[47872];
    _Float16* h_lds    = (_Float16*)smem;                  // [64][264] 33792 B
    _Float16* f_lds    = (_Float16*)(smem + 33792);        // 408 cells x16h, 13056 B
    float*    pos_lds  = (float*)(smem + 33792 + 13056);   // [64][4] 1024 B
    float*    part_lds = (float*)smem;                     // [64][106] alias

    const int t = threadIdx.x;
    // XCD-chunked swizzle: each XCD owns a contiguous slab of logical work
    const int bid = blockIdx.x;
    const int lb  = (bid & 7) * 512 + (bid >> 3);
    const int p0  = lb * 64;
    const int t2  = p0 >> 9;                  // output row oy
    const int hh  = t2 >> 1;
    const int ww0 = (p0 >> 1) & (WW - 1);

    if (t < 192) pos_lds[(t / 3) * 4 + (t % 3)] = pos[p0 * 3 + t];

    // stage f (f16 NHWC): 408 chunks = 4n x 3dy x 34x, one 32B chunk/thread
    if (t < 408) {
        int x = t % 34, nd = t / 34;
        int dy = nd % 3, n = nd / 3;
        int gy = hh + dy - 1, gx = ww0 + x - 1;
        uint4v v0 = {0u,0u,0u,0u}, v1 = {0u,0u,0u,0u};
        if (gy >= 0 && gy < HH && gx >= 0 && gx < WW) {
            const uint4v* src = (const uint4v*)&f[(((long)(n*HH+gy))*WW + gx) * 16];
            v0 = src[0]; v1 = src[1];
        }
        int cell = (((dy * 34 + x) * 4) + n) ^ (x & 7);
        uint4v* dst = (uint4v*)&f_lds[cell * 16];
        dst[0] = v0; dst[1] = v1;
    }
    __syncthreads();

    // ---- h = relu(pos @ w1 + b1), f16, padded row stride 264 ----
    {
        const int k  = t & 255;
        const int i0 = (t >> 8) * 32;
        float wa = w1[k], wb = w1[256 + k], wc = w1[512 + k], bb = b1[k];
#pragma unroll 8
        for (int i = i0; i < i0 + 32; ++i) {
            float4v pv = *(const float4v*)&pos_lds[i * 4];
            float a = fmaf(pv[0], wa, fmaf(pv[1], wb, fmaf(pv[2], wc, bb)));
            h_lds[i * 264 + k] = (_Float16)fmaxf(a, 0.f);
        }
    }
    __syncthreads();

    // ---- GEMM: acc[tt][pg] = w2tile(tb+tt)^T @ h(pg) ----
    const int wid  = t >> 6;
    const int lane = t & 63;
    const int l15  = lane & 15, hi = lane >> 4;
    const int tb   = (wid <= 3) ? wid * 4 : 12 + (wid - 3) * 3;
    const int cnt  = (wid < 3) ? 4 : 3;

    float4v acc[4][4];
#pragma unroll
    for (int tt = 0; tt < 4; ++tt)
        if (tt < cnt) {
            float4v binit = *(const float4v*)&b2p[(tb + tt) * 16 + hi * 4];
#pragma unroll
            for (int pg = 0; pg < 4; ++pg) acc[tt][pg] = binit;
        }

    for (int ks = 0; ks < 8; ++ks) {
        half8 bfrag[4];
#pragma unroll
        for (int pg = 0; pg < 4; ++pg)
            bfrag[pg] = *(const half8*)&h_lds[(pg * 16 + l15) * 264 + ks * 32 + hi * 8];
#pragma unroll
        for (int tt = 0; tt < 4; ++tt)
            if (tt < cnt) {
                half8 afrag = w2p[((tb + tt) * 8 + ks) * 64 + lane];
#pragma unroll
                for (int pg = 0; pg < 4; ++pg)
                    acc[tt][pg] = __builtin_amdgcn_mfma_f32_16x16x32_f16(
                        afrag, bfrag[pg], acc[tt][pg], 0, 0, 0);
            }
    }
    __syncthreads();   // all h reads done; part_lds (alias) may be written

    // ---- epilogue: dot2 contraction with f, reduce over hi and waves ------
    const int r3 = tb % 3;            // wave-uniform rgb rotation
    int dy_t[4], dx_t[4];
#pragma unroll
    for (int tt = 0; tt < 4; ++tt) {
        int kk = (tb + tt) / 3;
        dy_t[tt] = kk / 3;
        dx_t[tt] = kk % 3;
    }

#pragma unroll
    for (int pg = 0; pg < 4; ++pg) {
        const int posl = pg * 16 + l15;
        const int xloc = posl >> 1;

        float part[4][3];
#pragma unroll
        for (int n = 0; n < 4; ++n)
#pragma unroll
            for (int c = 0; c < 3; ++c) part[n][c] = 0.f;

#pragma unroll
        for (int tt = 0; tt < 4; ++tt)
            if (tt < cnt) {
                int x    = xloc + dx_t[tt];
                int key  = x & 7;
                int b4   = (dy_t[tt] * 34 + x) * 4;
                int basc = ((b4 ^ (key & 4)) << 4) + hi * 4;  // halfs
                int kn3  = (key & 3) << 4;
                half2v ap = pkrtz(acc[tt][pg][0], acc[tt][pg][1]);
                half2v bq = pkrtz(acc[tt][pg][2], acc[tt][pg][3]);
                const int u = tt % 3;
#pragma unroll
                for (int n = 0; n < 4; ++n) {
                    half4 fv = *(const half4*)&f_lds[basc + ((n << 4) ^ kn3)];
                    half2v flo = __builtin_shufflevector(fv, fv, 0, 1);
                    half2v fhi = __builtin_shufflevector(fv, fv, 2, 3);
                    part[n][u] = fdot2f(flo, ap, fdot2f(fhi, bq, part[n][u]));
                }
            }

        float real[4][3];
        if (r3 == 0) {
#pragma unroll
            for (int n = 0; n < 4; ++n) {
                real[n][0] = part[n][0]; real[n][1] = part[n][1]; real[n][2] = part[n][2];
            }
        } else if (r3 == 1) {
#pragma unroll
            for (int n = 0; n < 4; ++n) {
                real[n][1] = part[n][0]; real[n][2] = part[n][1]; real[n][0] = part[n][2];
            }
        } else {
#pragma unroll
            for (int n = 0; n < 4; ++n) {
                real[n][2] = part[n][0]; real[n][0] = part[n][1]; real[n][1] = part[n][2];
            }
        }

#pragma unroll
        for (int n = 0; n < 4; ++n)
#pragma unroll
            for (int c = 0; c < 3; ++c) {
                float v = real[n][c];
                v += __shfl_xor(v, 16);
                v += __shfl_xor(v, 32);
                if (hi == 0)
                    part_lds[posl * 106 + (n * 3 + c) * 8 + wid] = v;
            }
    }
    __syncthreads();

    // ---- combine 8 waves' partials, add mean, store ----
    for (int e = t; e < 768; e += 512) {
        int posl = e & 63;
        int j = e >> 6;                       // n*3+c
        const float* pr = &part_lds[posl * 106 + j * 8];
        float4v v0 = *(const float4v*)pr;
        float4v v1 = *(const float4v*)(pr + 4);
        float v = v0[0] + v0[1] + v0[2] + v0[3] + v1[0] + v1[1] + v1[2] + v1[3];
        int n = j / 3, c = j - 3 * n;
        float mean = (c == 0) ? 114.4440f : (c == 1) ? 111.4605f : 103.0200f;
        out[((n * 3 + c) * 512 + t2) * 512 + (ww0 * 2 + posl)] = v + mean;
    }
}

extern "C" void kernel_launch(void* const* d_in, const int* in_sizes, int n_in,
                              void* d_out, int out_size, void* d_ws, size_t ws_size,
                              hipStream_t stream) {
    const float* x    = (const float*)d_in[0];
    const float* pos  = (const float*)d_in[1];
    const float* c0w  = (const float*)d_in[2];
    const float* c1w  = (const float*)d_in[4];
    const float* c2w  = (const float*)d_in[6];
    const float* c3w  = (const float*)d_in[8];
    const float* c0b  = (const float*)d_in[3];
    const float* c1b  = (const float*)d_in[5];
    const float* c2b  = (const float*)d_in[7];
    const float* c3b  = (const float*)d_in[9];
    const float* w1   = (const float*)d_in[10];
    const float* b1   = (const float*)d_in[11];
    const float* w2   = (const float*)d_in[12];
    const float* b2   = (const float*)d_in[13];
    float* out = (float*)d_out;

    char* ws = (char*)d_ws;
    _Float16* xh = (_Float16*)ws;                         // 8 MB
    _Float16* fA = (_Float16*)(ws + (8u << 20));          // 8 MB
    _Float16* fB = (_Float16*)(ws + (16u << 20));         // 8 MB
    half8* w2p   = (half8*)(ws + (24u << 20));            // 221184 B
    float* b2p   = (float*)(ws + (24u << 20) + 221184);   // 1728 B
    half8* wpk   = (half8*)(ws + (24u << 20) + 221184 + 1728);  // 20480 B

    xcvt<<<1024, 256, 0, stream>>>(x, xh);
    pack_wc<<<5, 256, 0, stream>>>(c0w, c1w, c2w, c3w, wpk);
    pack_w2<<<54, 256, 0, stream>>>(w2, b2, w2p, b2p);

    conv_mfma<<<1024, 256, 0, stream>>>(xh, wpk,         c0b, fA);
    conv_mfma<<<1024, 256, 0, stream>>>(fA, wpk + 320,   c1b, fB);
    conv_mfma<<<1024, 256, 0, stream>>>(fB, wpk + 640,   c2b, fA);
    conv_mfma<<<1024, 256, 0, stream>>>(fA, wpk + 960,   c3b, fB);

    mlp_lc_mfma<<<4096, 512, 0, stream>>>(pos, w1, b1, w2p, b2p, fB, out);
}